// Round 3
// baseline (3914.076 us; speedup 1.0000x reference)
//
#include <hip/hip_runtime.h>

#define H    2048
#define NH   8
#define NKV  2
#define HD   256
#define DFF  4096
#define PLD  256
#define NL   8
#define WIN  512
#define FULLS 4096
#define EPS  1e-6f
#define ATT_SCALE 0.0625f
#define PLE_PROJ_SCALE 0.022097086912079608f  // 2048^-0.5
#define PLE_IN_SCALE   0.7071067811865476f    // 2^-0.5
#define MS   16
#define NB   512   // persistent grid: 512 blocks x 256 thr = 2 blocks/CU (capacity 4)

__device__ __forceinline__ float waveSum(float v) {
#pragma unroll
  for (int o = 32; o; o >>= 1) v += __shfl_xor(v, o);
  return v;
}
__device__ __forceinline__ float waveMax(float v) {
#pragma unroll
  for (int o = 32; o; o >>= 1) v = fmaxf(v, __shfl_xor(v, o));
  return v;
}
__device__ __forceinline__ float blockSum(float v) {
  __shared__ float red[4];
  int lane = threadIdx.x & 63, wid = threadIdx.x >> 6;
  v = waveSum(v);
  if (lane == 0) red[wid] = v;
  __syncthreads();
  float s = red[0] + red[1] + red[2] + red[3];
  __syncthreads();
  return s;
}
__device__ __forceinline__ float gelu_t(float x) {
  float x3 = x * x * x;
  return 0.5f * x * (1.f + tanhf(0.79788456080286536f * (x + 0.044715f * x3)));
}

// device-wide barrier: fresh counter per stage (zeroed each launch).
// __syncthreads drains all waves' vmem stores; t0's fence makes them
// agent-visible (L2 writeback); acquire-poll invalidates stale lines.
__device__ __forceinline__ void gbar(int* b) {
  __syncthreads();
  if (threadIdx.x == 0) {
    __threadfence();
    __hip_atomic_fetch_add(b, 1, __ATOMIC_ACQ_REL, __HIP_MEMORY_SCOPE_AGENT);
    while (__hip_atomic_load(b, __ATOMIC_ACQUIRE, __HIP_MEMORY_SCOPE_AGENT) < NB)
      __builtin_amdgcn_s_sleep(1);
  }
  __syncthreads();
}

template <int C>
__device__ __forceinline__ float dotrow(const float* __restrict__ w,
                                        const float* __restrict__ x, int lane) {
  float acc = 0.f;
#pragma unroll
  for (int c = lane * 4; c < C; c += 256) {
    float4 w4 = *(const float4*)(w + c);
    float4 x4 = *(const float4*)(x + c);
    acc = fmaf(w4.x, x4.x, fmaf(w4.y, x4.y, fmaf(w4.z, x4.z, fmaf(w4.w, x4.w, acc))));
  }
  return waveSum(acc);
}

struct MegaP {
  const float *hidden, *mask_full, *um, *plr, *cos_s, *sin_s, *cos_f, *sin_f;
  const float *Ksl, *Vsl, *Kfu, *Vfu;
  const float *Wq, *Wk, *Wv, *Wo, *qnw, *knw, *lin, *lpa, *lpf, *lpff;
  const float *Wg, *Wu, *Wd, *Wpg, *Wpp, *lpl, *lsc, *Wple, *plw;
  float *out, *outKs, *outVs, *outKf, *outVf;
  float *projb, *qkvb, *attnb, *wob, *actb, *dnb, *gatedb, *plb;
  float *hs_new, *hs2, *hs3, *part_o, *part_ml;
  int *bar, *cnt;
};

__global__ __launch_bounds__(256, 4) void k_mega(MegaP p) {
  const int t = threadIdx.x, lane = t & 63, wid = t >> 6, b = blockIdx.x;
  const int gw = b * 4 + wid;          // 0..2047
  int sid = 0;

  __shared__ __align__(16) float xs[2048];
  __shared__ __align__(16) float s_kr[2][256], s_v[2][256], s_q[256], s_qt[256];
  __shared__ float s_sc[64], s_ml[2];
  __shared__ int s_last;

  // ================= Stage A: PLE projection (2048 rows x 2048) =============
  if (gw < 2048) {
    float s = dotrow<2048>(p.Wple + (size_t)gw * H, p.hidden, lane);
    if (lane == 0) p.projb[gw] = s * PLE_PROJ_SCALE;
  }
  gbar(p.bar + sid++);

  for (int li = 0; li < NL; li++) {
    const bool isf = (li % 5 == 4);
    const float* cosp = isf ? p.cos_f : p.cos_s;
    const float* sinp = isf ? p.sin_f : p.sin_s;
    float* qkvL = p.qkvb + li * 3072;

    // ============ Stage B: hs_new, xs = rms(hs_new)*w_in, QKV GEMV ==========
    {
      float e[8];
      if (li == 0) {
#pragma unroll
        for (int k = 0; k < 8; k++) e[k] = p.hidden[t + 256 * k];
      } else {
        const float* pl  = p.plb + (li - 1) * 2048;
        const float* wpl = p.lpl + (size_t)(li - 1) * 2048;
        const float* hp  = p.hs3 + (li - 1) * 2048;
        float plv[8]; float ss = 0.f;
#pragma unroll
        for (int k = 0; k < 8; k++) { plv[k] = pl[t + 256 * k]; ss += plv[k] * plv[k]; }
        float r1 = rsqrtf(blockSum(ss) * (1.f / 2048.f) + EPS);
        float sc = p.lsc[li - 1];
#pragma unroll
        for (int k = 0; k < 8; k++) {
          int idx = t + 256 * k;
          e[k] = (hp[idx] + plv[k] * r1 * wpl[idx]) * sc;
        }
      }
      float ss2 = 0.f;
#pragma unroll
      for (int k = 0; k < 8; k++) ss2 += e[k] * e[k];
      float r2 = rsqrtf(blockSum(ss2) * (1.f / 2048.f) + EPS);
      const float* w_in = p.lin + (size_t)li * 2048;
      float* hsN = p.hs_new + li * 2048;
#pragma unroll
      for (int k = 0; k < 8; k++) {
        int idx = t + 256 * k;
        xs[idx] = e[k] * r2 * w_in[idx];
        if (b == 0) hsN[idx] = e[k];
      }
      __syncthreads();
      {
        const float* wr = p.Wq + ((size_t)li * 2048 + gw) * H;
        float s = dotrow<2048>(wr, xs, lane);
        if (lane == 0) qkvL[gw] = s;
      }
      if (gw < 1024) {
        int r2i = 2048 + gw;
        const float* wr = (r2i < 2560)
            ? p.Wk + ((size_t)li * 512 + (r2i - 2048)) * H
            : p.Wv + ((size_t)li * 512 + (r2i - 2560)) * H;
        float s = dotrow<2048>(wr, xs, lane);
        if (lane == 0) qkvL[r2i] = s;
      }
    }
    gbar(p.bar + sid++);

    // ============ Stage C: attention tasks + cache-update tasks =============
    {
      const int S = isf ? FULLS : WIN;
      const int nsp = isf ? 16 : 8;          // attended splits (full: j<1024 only)
      const int natt = NH * nsp;
      const int ncache = isf ? 512 : 64;     // tasks of 2048 float4 each
      const int ntask = natt + ncache;
      const int si = (li < 4) ? li : li - 1;
      const float* Kin = isf ? p.Kfu : p.Ksl + (size_t)si * 2 * WIN * HD;
      const float* Vin = isf ? p.Vfu : p.Vsl + (size_t)si * 2 * WIN * HD;
      float* Ko = isf ? p.outKf : p.outKs + (size_t)si * 2 * WIN * HD;
      float* Vo = isf ? p.outVf : p.outVs + (size_t)si * 2 * WIN * HD;
      float* pO  = p.part_o  + (size_t)li * (NH * MS * 256);
      float* pML = p.part_ml + li * (NH * MS * 2);

      if (b < ntask) {
        // prologue: k rms+rope, v vnorm for both kv heads
        for (int c = 0; c < 2; c++) {
          float kvv = qkvL[2048 + c * 256 + t];
          float rk = rsqrtf(blockSum(kvv * kvv) * (1.f / 256.f) + EPS);
          float kn = kvv * rk * p.knw[li * 256 + t];
          s_qt[t] = kn;
          float vv = qkvL[2560 + c * 256 + t];
          float rv = rsqrtf(blockSum(vv * vv) * (1.f / 256.f) + EPS);  // syncs: s_qt visible
          float rot = (t < 128) ? -s_qt[t + 128] : s_qt[t - 128];
          s_kr[c][t] = kn * cosp[t] + rot * sinp[t];
          s_v[c][t] = vv * rv;
          __syncthreads();
        }
        for (int task = b; task < ntask; task += NB) {
          if (task < natt) {
            const int h = task / nsp, split = task % nsp, kvh = h >> 2;
            const int j0 = split * 64;
            __syncthreads();
            float qv = qkvL[h * 256 + t];
            float rq = rsqrtf(blockSum(qv * qv) * (1.f / 256.f) + EPS);
            float qn = qv * rq * p.qnw[li * 256 + t];
            s_qt[t] = qn;
            __syncthreads();
            float rot = (t < 128) ? -s_qt[t + 128] : s_qt[t - 128];
            s_q[t] = qn * cosp[t] + rot * sinp[t];
            __syncthreads();
            // scores
            float4 q4 = ((const float4*)s_q)[lane];
            for (int jl = wid; jl < 64; jl += 4) {
              int j = j0 + jl;
              float4 k4;
              if (!isf) {
                k4 = (j < S - 1) ? ((const float4*)Kin)[((size_t)kvh * S + j + 1) * 64 + lane]
                                 : ((const float4*)s_kr[kvh])[lane];
              } else {
                k4 = ((const float4*)Kin)[((size_t)kvh * S + j) * 64 + lane];
                float u = p.um[j];
                if (u != 0.f) {
                  float om = 1.f - u;
                  float4 nk = ((const float4*)s_kr[kvh])[lane];
                  k4.x = k4.x * om + nk.x * u; k4.y = k4.y * om + nk.y * u;
                  k4.z = k4.z * om + nk.z * u; k4.w = k4.w * om + nk.w * u;
                }
              }
              float pp = q4.x * k4.x + q4.y * k4.y + q4.z * k4.z + q4.w * k4.w;
              pp = waveSum(pp);
              if (lane == 0) s_sc[jl] = pp * ATT_SCALE + (isf ? p.mask_full[j] : 0.f);
            }
            __syncthreads();
            if (wid == 0) {
              float v = s_sc[lane];
              float m = waveMax(v);
              float e = expf(v - m);
              s_sc[lane] = e;
              float l = waveSum(e);
              if (lane == 0) { s_ml[0] = m; s_ml[1] = l; }
            }
            __syncthreads();
            // PV
            float o = 0.f;
#pragma unroll 8
            for (int jl = 0; jl < 64; jl++) {
              int j = j0 + jl;
              float vj;
              if (!isf) {
                vj = (j < S - 1) ? Vin[((size_t)kvh * S + j + 1) * 256 + t] : s_v[kvh][t];
              } else {
                vj = Vin[((size_t)kvh * S + j) * 256 + t];
                float u = p.um[j];
                if (u != 0.f) vj = vj * (1.f - u) + s_v[kvh][t] * u;
              }
              o = fmaf(s_sc[jl], vj, o);
            }
            pO[((size_t)h * MS + split) * 256 + t] = o;
            if (t < 2) pML[(h * MS + split) * 2 + t] = s_ml[t];
            __syncthreads();           // drain ALL waves' stores before the elect
            if (t == 0) {
              __threadfence();
              int old = atomicAdd(p.cnt + li * NH + h, 1);
              s_last = (old == nsp - 1);
            }
            __syncthreads();
            if (s_last) {
              __threadfence();
              float M = -INFINITY;
              for (int s2 = 0; s2 < nsp; s2++) M = fmaxf(M, pML[(h * MS + s2) * 2]);
              float L = 0.f, oo = 0.f;
              for (int s2 = 0; s2 < nsp; s2++) {
                float m = pML[(h * MS + s2) * 2];
                float l = pML[(h * MS + s2) * 2 + 1];
                float f = expf(m - M);
                L += l * f;
                oo = fmaf(pO[((size_t)h * MS + s2) * 256 + t], f, oo);
              }
              p.attnb[li * 2048 + h * 256 + t] = oo / L;
            }
          } else {
            // cache task: 2048 float4 slice of [K|V][kv][pos][64]
            int ci = task - natt;
            const int fK = 2 * S * 64;
            const float4* Ki4 = (const float4*)Kin;
            const float4* Vi4 = (const float4*)Vin;
            float4* Ko4 = (float4*)Ko;
            float4* Vo4 = (float4*)Vo;
#pragma unroll
            for (int k = 0; k < 8; k++) {
              int idx = ci * 2048 + k * 256 + t;
              int isV = idx >= fK;
              int rid = isV ? idx - fK : idx;
              int kvh = rid / (S * 64);
              int rem = rid % (S * 64);
              int j = rem >> 6, d4 = rem & 63;
              const float4* in4 = isV ? Vi4 : Ki4;
              const float4* nn4 = (const float4*)(isV ? s_v[kvh] : s_kr[kvh]);
              float4 v;
              if (!isf) {
                v = (j < S - 1) ? in4[((size_t)kvh * S + j + 1) * 64 + d4] : nn4[d4];
              } else {
                v = in4[rid];
                float u = p.um[j];
                if (u != 0.f) {
                  float om = 1.f - u;
                  float4 nv = nn4[d4];
                  v.x = v.x * om + nv.x * u; v.y = v.y * om + nv.y * u;
                  v.z = v.z * om + nv.z * u; v.w = v.w * om + nv.w * u;
                }
              }
              (isV ? Vo4 : Ko4)[rid] = v;
            }
          }
        }
      }
    }
    gbar(p.bar + sid++);

    // ============ Stage D: Wo GEMV (2048 x 2048) ============================
    {
      const float* x = p.attnb + li * 2048;
      const float* wr = p.Wo + ((size_t)li * 2048 + gw) * H;
      float s = dotrow<2048>(wr, x, lane);
      if (lane == 0) p.wob[li * 2048 + gw] = s;
    }
    gbar(p.bar + sid++);

    // ============ Stage E: hs2, xs = rms(hs2)*w_pf, gate/up GEMV ============
    {
      const float* hsN = p.hs_new + li * 2048;
      const float* wo = p.wob + li * 2048;
      const float* w_pa = p.lpa + (size_t)li * 2048;
      const float* w_pf = p.lpf + (size_t)li * 2048;
      float wv[8]; float ss = 0.f;
#pragma unroll
      for (int k = 0; k < 8; k++) { wv[k] = wo[t + 256 * k]; ss += wv[k] * wv[k]; }
      float r1 = rsqrtf(blockSum(ss) * (1.f / 2048.f) + EPS);
      float e[8]; float ss2 = 0.f;
#pragma unroll
      for (int k = 0; k < 8; k++) {
        int idx = t + 256 * k;
        e[k] = hsN[idx] + wv[k] * r1 * w_pa[idx];
        ss2 += e[k] * e[k];
      }
      float r2 = rsqrtf(blockSum(ss2) * (1.f / 2048.f) + EPS);
      float* hs2L = p.hs2 + li * 2048;
#pragma unroll
      for (int k = 0; k < 8; k++) {
        int idx = t + 256 * k;
        xs[idx] = e[k] * r2 * w_pf[idx];
        if (b == 0) hs2L[idx] = e[k];
      }
      __syncthreads();
      for (int rr = 0; rr < 2; rr++) {
        int row = gw + rr * 2048;
        const float* g = p.Wg + ((size_t)li * 4096 + row) * H;
        const float* u = p.Wu + ((size_t)li * 4096 + row) * H;
        float ag = 0.f, au = 0.f;
#pragma unroll
        for (int c = lane * 4; c < 2048; c += 256) {
          float4 x4 = *(const float4*)(xs + c);
          float4 g4 = *(const float4*)(g + c);
          float4 u4 = *(const float4*)(u + c);
          ag = fmaf(g4.x, x4.x, fmaf(g4.y, x4.y, fmaf(g4.z, x4.z, fmaf(g4.w, x4.w, ag))));
          au = fmaf(u4.x, x4.x, fmaf(u4.y, x4.y, fmaf(u4.z, x4.z, fmaf(u4.w, x4.w, au))));
        }
        ag = waveSum(ag); au = waveSum(au);
        if (lane == 0) p.actb[li * 4096 + row] = gelu_t(ag) * au;
      }
    }
    gbar(p.bar + sid++);

    // ============ Stage F: down GEMV (2048 x 4096) ==========================
    {
      const float* x = p.actb + li * 4096;
      const float* wr = p.Wd + ((size_t)li * 2048 + gw) * DFF;
      float s = dotrow<4096>(wr, x, lane);
      if (lane == 0) p.dnb[li * 2048 + gw] = s;
    }
    gbar(p.bar + sid++);

    // ============ Stage G: hs3, sl, pl-gate GEMV (256 x 2048) ===============
    if (b < 64) {
      const float* hs2L = p.hs2 + li * 2048;
      const float* dn = p.dnb + li * 2048;
      const float* w_pff = p.lpff + (size_t)li * 2048;
      float dv[8]; float ss = 0.f;
#pragma unroll
      for (int k = 0; k < 8; k++) { dv[k] = dn[t + 256 * k]; ss += dv[k] * dv[k]; }
      float r1 = rsqrtf(blockSum(ss) * (1.f / 2048.f) + EPS);
      float* hs3L = p.hs3 + li * 2048;
#pragma unroll
      for (int k = 0; k < 8; k++) {
        int idx = t + 256 * k;
        float e = hs2L[idx] + dv[k] * r1 * w_pff[idx];
        xs[idx] = e;
        if (b == 0) hs3L[idx] = e;
      }
      float pv = p.projb[li * 256 + t];
      float rp = rsqrtf(blockSum(pv * pv) * (1.f / 256.f) + EPS);
      s_qt[t] = (pv * rp * p.plw[t] + p.plr[li * 256 + t]) * PLE_IN_SCALE;
      __syncthreads();
      int row = gw;  // 0..255
      const float* wr = p.Wpg + ((size_t)li * 256 + row) * H;
      float acc = dotrow<2048>(wr, xs, lane);
      if (lane == 0) p.gatedb[li * 256 + row] = gelu_t(acc) * s_qt[row];
    }
    gbar(p.bar + sid++);

    // ============ Stage H: Wpp GEMV (2048 x 256) ============================
    {
      const float* x = p.gatedb + li * 256;
      const float* wr = p.Wpp + ((size_t)li * 2048 + gw) * PLD;
      float s = dotrow<256>(wr, x, lane);
      if (lane == 0) p.plb[li * 2048 + gw] = s;
    }
    gbar(p.bar + sid++);
  }

  // ================= final: out = (hs3 + rms(pl)*w_pl) * lsc[7] =============
  if (b == 0) {
    const float* pl = p.plb + 7 * 2048;
    const float* wpl = p.lpl + (size_t)7 * 2048;
    const float* hs3L = p.hs3 + 7 * 2048;
    float pv[8]; float ss = 0.f;
#pragma unroll
    for (int k = 0; k < 8; k++) { pv[k] = pl[t + 256 * k]; ss += pv[k] * pv[k]; }
    float r = rsqrtf(blockSum(ss) * (1.f / 2048.f) + EPS);
    float sc = p.lsc[NL - 1];
#pragma unroll
    for (int k = 0; k < 8; k++) {
      int idx = t + 256 * k;
      p.out[idx] = (hs3L[idx] + pv[k] * r * wpl[idx]) * sc;
    }
  }
}

extern "C" void kernel_launch(void* const* d_in, const int* in_sizes, int n_in,
                              void* d_out, int out_size, void* d_ws, size_t ws_size,
                              hipStream_t stream) {
  MegaP p;
  p.hidden     = (const float*)d_in[0];
  p.mask_full  = (const float*)d_in[1];
  p.um         = (const float*)d_in[3];
  p.plr        = (const float*)d_in[4];
  p.cos_s      = (const float*)d_in[5];
  p.sin_s      = (const float*)d_in[6];
  p.cos_f      = (const float*)d_in[7];
  p.sin_f      = (const float*)d_in[8];
  p.Ksl        = (const float*)d_in[9];
  p.Vsl        = (const float*)d_in[10];
  p.Kfu        = (const float*)d_in[11];
  p.Vfu        = (const float*)d_in[12];
  p.Wq         = (const float*)d_in[13];
  p.Wk         = (const float*)d_in[14];
  p.Wv         = (const float*)d_in[15];
  p.Wo         = (const float*)d_in[16];
  p.qnw        = (const float*)d_in[17];
  p.knw        = (const float*)d_in[18];
  p.lin        = (const float*)d_in[19];
  p.lpa        = (const float*)d_in[20];
  p.lpf        = (const float*)d_in[21];
  p.lpff       = (const float*)d_in[22];
  p.Wg         = (const float*)d_in[23];
  p.Wu         = (const float*)d_in[24];
  p.Wd         = (const float*)d_in[25];
  p.Wpg        = (const float*)d_in[26];
  p.Wpp        = (const float*)d_in[27];
  p.lpl        = (const float*)d_in[28];
  p.lsc        = (const float*)d_in[29];
  p.Wple       = (const float*)d_in[30];
  p.plw        = (const float*)d_in[31];

  float* out = (float*)d_out;
  const size_t KS_SZ = (size_t)7 * 2 * WIN * HD;
  const size_t KF_SZ = (size_t)2 * FULLS * HD;
  p.out   = out;
  p.outKs = out + 2048;
  p.outVs = p.outKs + KS_SZ;
  p.outKf = p.outVs + KS_SZ;
  p.outVf = p.outKf + KF_SZ;

  float* ws = (float*)d_ws;
  p.bar = (int*)ws;                 // 64 ints
  p.cnt = (int*)ws + 64;            // 64 ints
  float* f = ws + 128;
  p.projb  = f;  f += 2048;
  p.qkvb   = f;  f += NL * 3072;
  p.attnb  = f;  f += NL * 2048;
  p.wob    = f;  f += NL * 2048;
  p.actb   = f;  f += NL * 4096;
  p.dnb    = f;  f += NL * 2048;
  p.gatedb = f;  f += NL * 256;
  p.plb    = f;  f += NL * 2048;
  p.hs_new = f;  f += NL * 2048;
  p.hs2    = f;  f += NL * 2048;
  p.hs3    = f;  f += NL * 2048;
  p.part_o = f;  f += (size_t)NL * NH * MS * 256;
  p.part_ml= f;  f += NL * NH * MS * 2;

  hipMemsetAsync(ws, 0, 128 * sizeof(int), stream);
  k_mega<<<NB, 256, 0, stream>>>(p);
}

// Round 5
// 2492.204 us; speedup vs baseline: 1.5705x; 1.5705x over previous
//
#include <hip/hip_runtime.h>

#define H    2048
#define NH   8
#define NKV  2
#define HD   256
#define DFF  4096
#define PLD  256
#define NL   8
#define WIN  512
#define FULLS 4096
#define EPS  1e-6f
#define ATT_SCALE 0.0625f
#define PLE_PROJ_SCALE 0.022097086912079608f  // 2048^-0.5
#define PLE_IN_SCALE   0.7071067811865476f    // 2^-0.5
#define MS   16
#define NB   512              // persistent grid (2 blocks/CU, proven co-resident r3)
#define NWAVE 2048            // NB*4
#define NGRP 32
#define GSZ  16               // NB/NGRP
#define NSID 56               // barriers: 7 per layer * 8 layers

__device__ __forceinline__ float waveSum(float v) {
#pragma unroll
  for (int o = 32; o; o >>= 1) v += __shfl_xor(v, o);
  return v;
}
__device__ __forceinline__ float waveMax(float v) {
#pragma unroll
  for (int o = 32; o; o >>= 1) v = fmaxf(v, __shfl_xor(v, o));
  return v;
}
__device__ __forceinline__ float blockSum(float v) {
  __shared__ float red[4];
  int lane = threadIdx.x & 63, wid = threadIdx.x >> 6;
  v = waveSum(v);
  if (lane == 0) red[wid] = v;
  __syncthreads();
  float s = red[0] + red[1] + red[2] + red[3];
  __syncthreads();
  return s;
}
__device__ __forceinline__ float gelu_t(float x) {
  float x3 = x * x * x;
  return 0.5f * x * (1.f + tanhf(0.79788456080286536f * (x + 0.044715f * x3)));
}

// ---- device-wide barrier v2: tree arrivals (ACQ_REL on padded lines),
// ---- RELAXED polling (no per-poll L2 invalidate!), single ACQUIRE fence on exit.
__device__ __forceinline__ void gbar(int* cnt, int* top, int* go, int sid) {
  __syncthreads();
  if (threadIdx.x == 0) {
    const int grp = blockIdx.x >> 4;   // /GSZ
    int old = __hip_atomic_fetch_add(cnt + (sid * NGRP + grp) * 32, 1,
                                     __ATOMIC_ACQ_REL, __HIP_MEMORY_SCOPE_AGENT);
    if (old == GSZ - 1) {
      int o2 = __hip_atomic_fetch_add(top + sid * 32, 1,
                                      __ATOMIC_ACQ_REL, __HIP_MEMORY_SCOPE_AGENT);
      if (o2 == NGRP - 1) {
        for (int g = 0; g < NGRP; g++)
          __hip_atomic_store(go + g * 32, sid + 1, __ATOMIC_RELEASE,
                             __HIP_MEMORY_SCOPE_AGENT);
      }
    }
    while (__hip_atomic_load(go + grp * 32, __ATOMIC_RELAXED,
                             __HIP_MEMORY_SCOPE_AGENT) <= sid)
      __builtin_amdgcn_s_sleep(4);
    __builtin_amdgcn_fence(__ATOMIC_ACQUIRE, "agent");
  }
  __syncthreads();
}

__device__ __forceinline__ float dot4(float4 w, float4 x, float acc) {
  return fmaf(w.x, x.x, fmaf(w.y, x.y, fmaf(w.z, x.z, fmaf(w.w, x.w, acc))));
}

template <int C>
__device__ __forceinline__ float dotrow(const float* __restrict__ w,
                                        const float* __restrict__ x, int lane) {
  float acc = 0.f;
#pragma unroll
  for (int c = lane * 4; c < C; c += 256)
    acc = dot4(*(const float4*)(w + c), *(const float4*)(x + c), acc);
  return waveSum(acc);
}
template <int NPF>
__device__ __forceinline__ void prefetch_row(const float* __restrict__ w, int lane,
                                             float4* pre) {
#pragma unroll
  for (int k = 0; k < NPF; k++) pre[k] = *(const float4*)(w + lane * 4 + k * 256);
}
template <int NPF>
__device__ __forceinline__ float dot_pre(const float4* pre, const float* __restrict__ x,
                                         int lane) {
  float acc = 0.f;
#pragma unroll
  for (int k = 0; k < NPF; k++)
    acc = dot4(pre[k], *(const float4*)(x + lane * 4 + k * 256), acc);
  return acc;
}
template <int C, int OFS>
__device__ __forceinline__ float dot_rest(const float* __restrict__ w,
                                          const float* __restrict__ x, int lane,
                                          float acc) {
#pragma unroll
  for (int c = OFS + lane * 4; c < C; c += 256)
    acc = dot4(*(const float4*)(w + c), *(const float4*)(x + c), acc);
  return acc;
}

struct MegaP {
  const float *hidden, *mask_full, *um, *plr, *cos_s, *sin_s, *cos_f, *sin_f;
  const float *Ksl, *Vsl, *Kfu, *Vfu;
  const float *Wq, *Wk, *Wv, *Wo, *qnw, *knw, *lin, *lpa, *lpf, *lpff;
  const float *Wg, *Wu, *Wd, *Wpg, *Wpp, *lpl, *lsc, *Wple, *plw;
  float *out, *outKs, *outVs, *outKf, *outVf;
  float *projb, *qkvb, *attnb, *wob, *actb, *dnb, *gatedb, *plb;
  float *hs_new, *hs2, *hs3, *part_o, *part_ml;
  int *cnt, *top, *go, *acnt;
};

__global__ __launch_bounds__(256, 2) void k_mega(MegaP p) {
  const int t = threadIdx.x, lane = t & 63, wid = t >> 6, b = blockIdx.x;
  const int gw = b * 4 + wid;          // 0..2047
  int sid = 0;

  __shared__ __align__(16) float xs[2048];
  __shared__ __align__(16) float s_kr[2][256], s_v[2][256], s_q[256], s_qt[256];
  __shared__ float s_sc[64], s_ml[2];
  __shared__ int s_last;

  float4 preB[8];
  bool hasB = false;

  for (int li = 0; li < NL; li++) {
    const bool isf = (li % 5 == 4);
    const float* cosp = isf ? p.cos_f : p.cos_s;
    const float* sinp = isf ? p.sin_f : p.sin_s;
    float* qkvL = p.qkvb + li * 3072;

    // ============ Stage B: hs_new, xs = rms(hs_new)*w_in, QKV (+PLE at li=0) ====
    {
      float e[8];
      if (li == 0) {
#pragma unroll
        for (int k = 0; k < 8; k++) e[k] = p.hidden[t + 256 * k];
      } else {
        const float* pl  = p.plb + (li - 1) * 2048;
        const float* wpl = p.lpl + (size_t)(li - 1) * 2048;
        const float* hp  = p.hs3 + (li - 1) * 2048;
        float plv[8]; float ss = 0.f;
#pragma unroll
        for (int k = 0; k < 8; k++) { plv[k] = pl[t + 256 * k]; ss += plv[k] * plv[k]; }
        float r1 = rsqrtf(blockSum(ss) * (1.f / 2048.f) + EPS);
        float sc = p.lsc[li - 1];
#pragma unroll
        for (int k = 0; k < 8; k++) {
          int idx = t + 256 * k;
          e[k] = (hp[idx] + plv[k] * r1 * wpl[idx]) * sc;
        }
      }
      float ss2 = 0.f;
#pragma unroll
      for (int k = 0; k < 8; k++) ss2 += e[k] * e[k];
      float r2 = rsqrtf(blockSum(ss2) * (1.f / 2048.f) + EPS);
      const float* w_in = p.lin + (size_t)li * 2048;
      float* hsN = p.hs_new + li * 2048;
#pragma unroll
      for (int k = 0; k < 8; k++) {
        int idx = t + 256 * k;
        xs[idx] = e[k] * r2 * w_in[idx];
        if (b == 0) hsN[idx] = e[k];
      }
      __syncthreads();
      const int nrows = (li == 0) ? 5120 : 3072;
      for (int row = gw; row < nrows; row += NWAVE) {
        const float* wr; const float* xsrc = xs; float* dst; float sc2 = 1.f;
        if (row < 2048)      { wr = p.Wq + ((size_t)li * 2048 + row) * H; dst = qkvL + row; }
        else if (row < 2560) { wr = p.Wk + ((size_t)li * 512 + (row - 2048)) * H; dst = qkvL + row; }
        else if (row < 3072) { wr = p.Wv + ((size_t)li * 512 + (row - 2560)) * H; dst = qkvL + row; }
        else { wr = p.Wple + (size_t)(row - 3072) * H; xsrc = p.hidden;
               dst = p.projb + (row - 3072); sc2 = PLE_PROJ_SCALE; }
        float s;
        if (row == gw && hasB) s = waveSum(dot_pre<8>(preB, xsrc, lane));
        else                   s = dotrow<2048>(wr, xsrc, lane);
        if (lane == 0) *dst = s * sc2;
      }
    }
    gbar(p.cnt, p.top, p.go, sid); sid++;

    // ============ Stage C: attention tasks + cache-update tasks =============
    {
      const int S = isf ? FULLS : WIN;
      const int nsp = isf ? 16 : 8;          // attended splits (full: j<1024 only)
      const int natt = NH * nsp;
      const int ncache = isf ? 256 : 32;     // tasks of 4096 float4 each
      const int ntask = natt + ncache;
      const int si = (li < 4) ? li : li - 1;
      const float* Kin = isf ? p.Kfu : p.Ksl + (size_t)si * 2 * WIN * HD;
      const float* Vin = isf ? p.Vfu : p.Vsl + (size_t)si * 2 * WIN * HD;
      float* Ko = isf ? p.outKf : p.outKs + (size_t)si * 2 * WIN * HD;
      float* Vo = isf ? p.outVf : p.outVs + (size_t)si * 2 * WIN * HD;
      float* pO  = p.part_o  + (size_t)li * (NH * MS * 256);
      float* pML = p.part_ml + li * (NH * MS * 2);

      if (b < ntask) {
        // prologue: k rms+rope, v vnorm for both kv heads
        for (int c = 0; c < 2; c++) {
          float kvv = qkvL[2048 + c * 256 + t];
          float rk = rsqrtf(blockSum(kvv * kvv) * (1.f / 256.f) + EPS);
          float kn = kvv * rk * p.knw[li * 256 + t];
          s_qt[t] = kn;
          float vv = qkvL[2560 + c * 256 + t];
          float rv = rsqrtf(blockSum(vv * vv) * (1.f / 256.f) + EPS);  // syncs s_qt
          float rot = (t < 128) ? -s_qt[t + 128] : s_qt[t - 128];
          s_kr[c][t] = kn * cosp[t] + rot * sinp[t];
          s_v[c][t] = vv * rv;
          __syncthreads();
        }
        const int task = b;
        if (task < natt) {
          const int h = task / nsp, split = task % nsp, kvh = h >> 2;
          const int j0 = split * 64;
          float qv = qkvL[h * 256 + t];
          float rq = rsqrtf(blockSum(qv * qv) * (1.f / 256.f) + EPS);
          float qn = qv * rq * p.qnw[li * 256 + t];
          s_qt[t] = qn;
          __syncthreads();
          float rot = (t < 128) ? -s_qt[t + 128] : s_qt[t - 128];
          s_q[t] = qn * cosp[t] + rot * sinp[t];
          __syncthreads();
          // scores
          float4 q4 = ((const float4*)s_q)[lane];
          for (int jl = wid; jl < 64; jl += 4) {
            int j = j0 + jl;
            float4 k4;
            if (!isf) {
              k4 = (j < S - 1) ? ((const float4*)Kin)[((size_t)kvh * S + j + 1) * 64 + lane]
                               : ((const float4*)s_kr[kvh])[lane];
            } else {
              k4 = ((const float4*)Kin)[((size_t)kvh * S + j) * 64 + lane];
              float u = p.um[j];
              if (u != 0.f) {
                float om = 1.f - u;
                float4 nk = ((const float4*)s_kr[kvh])[lane];
                k4.x = k4.x * om + nk.x * u; k4.y = k4.y * om + nk.y * u;
                k4.z = k4.z * om + nk.z * u; k4.w = k4.w * om + nk.w * u;
              }
            }
            float pp = q4.x * k4.x + q4.y * k4.y + q4.z * k4.z + q4.w * k4.w;
            pp = waveSum(pp);
            if (lane == 0) s_sc[jl] = pp * ATT_SCALE + (isf ? p.mask_full[j] : 0.f);
          }
          __syncthreads();
          if (wid == 0) {
            float v = s_sc[lane];
            float m = waveMax(v);
            float e = expf(v - m);
            s_sc[lane] = e;
            float l = waveSum(e);
            if (lane == 0) { s_ml[0] = m; s_ml[1] = l; }
          }
          __syncthreads();
          // PV
          float o = 0.f;
#pragma unroll 8
          for (int jl = 0; jl < 64; jl++) {
            int j = j0 + jl;
            float vj;
            if (!isf) {
              vj = (j < S - 1) ? Vin[((size_t)kvh * S + j + 1) * 256 + t] : s_v[kvh][t];
            } else {
              vj = Vin[((size_t)kvh * S + j) * 256 + t];
              float u = p.um[j];
              if (u != 0.f) vj = vj * (1.f - u) + s_v[kvh][t] * u;
            }
            o = fmaf(s_sc[jl], vj, o);
          }
          pO[((size_t)h * MS + split) * 256 + t] = o;
          if (t < 2) pML[(h * MS + split) * 2 + t] = s_ml[t];
          __syncthreads();           // drain all waves' stores before the elect
          if (t == 0) {
            __threadfence();
            int old = atomicAdd(p.acnt + li * NH + h, 1);
            s_last = (old == nsp - 1);
          }
          __syncthreads();
          if (s_last) {
            __threadfence();
            float M = -INFINITY;
            for (int s2 = 0; s2 < nsp; s2++) M = fmaxf(M, pML[(h * MS + s2) * 2]);
            float L = 0.f, oo = 0.f;
            for (int s2 = 0; s2 < nsp; s2++) {
              float m = pML[(h * MS + s2) * 2];
              float l = pML[(h * MS + s2) * 2 + 1];
              float f = expf(m - M);
              L += l * f;
              oo = fmaf(pO[((size_t)h * MS + s2) * 256 + t], f, oo);
            }
            p.attnb[li * 2048 + h * 256 + t] = oo / L;
          }
        } else {
          // cache task: 4096 float4 slice of [K|V][kv][pos][64]
          int ci = task - natt;
          const int fK = 2 * S * 64;
          const float4* Ki4 = (const float4*)Kin;
          const float4* Vi4 = (const float4*)Vin;
          float4* Ko4 = (float4*)Ko;
          float4* Vo4 = (float4*)Vo;
#pragma unroll
          for (int k = 0; k < 16; k++) {
            int idx = ci * 4096 + k * 256 + t;
            int isV = idx >= fK;
            int rid = isV ? idx - fK : idx;
            int kvh = rid / (S * 64);
            int rem = rid % (S * 64);
            int j = rem >> 6, d4 = rem & 63;
            const float4* in4 = isV ? Vi4 : Ki4;
            const float4* nn4 = (const float4*)(isV ? s_v[kvh] : s_kr[kvh]);
            float4 v;
            if (!isf) {
              v = (j < S - 1) ? in4[((size_t)kvh * S + j + 1) * 64 + d4] : nn4[d4];
            } else {
              v = in4[rid];
              float u = p.um[j];
              if (u != 0.f) {
                float om = 1.f - u;
                float4 nv = nn4[d4];
                v.x = v.x * om + nv.x * u; v.y = v.y * om + nv.y * u;
                v.z = v.z * om + nv.z * u; v.w = v.w * om + nv.w * u;
              }
            }
            (isV ? Vo4 : Ko4)[rid] = v;
          }
        }
      }
    }
    // prefetch Wo row for stage D (flies during the barrier)
    float4 preD[8];
    prefetch_row<8>(p.Wo + ((size_t)li * 2048 + gw) * H, lane, preD);
    gbar(p.cnt, p.top, p.go, sid); sid++;

    // ============ Stage D: Wo GEMV (2048 x 2048) ============================
    {
      float s = waveSum(dot_pre<8>(preD, p.attnb + li * 2048, lane));
      if (lane == 0) p.wob[li * 2048 + gw] = s;
    }
    float4 preG4[4], preU4[4];
    prefetch_row<4>(p.Wg + ((size_t)li * 4096 + gw) * H, lane, preG4);
    prefetch_row<4>(p.Wu + ((size_t)li * 4096 + gw) * H, lane, preU4);
    gbar(p.cnt, p.top, p.go, sid); sid++;

    // ============ Stage E: hs2, xs = rms(hs2)*w_pf, gate/up GEMV ============
    {
      const float* hsN = p.hs_new + li * 2048;
      const float* wo = p.wob + li * 2048;
      const float* w_pa = p.lpa + (size_t)li * 2048;
      const float* w_pf = p.lpf + (size_t)li * 2048;
      float wv[8]; float ss = 0.f;
#pragma unroll
      for (int k = 0; k < 8; k++) { wv[k] = wo[t + 256 * k]; ss += wv[k] * wv[k]; }
      float r1 = rsqrtf(blockSum(ss) * (1.f / 2048.f) + EPS);
      float e[8]; float ss2 = 0.f;
#pragma unroll
      for (int k = 0; k < 8; k++) {
        int idx = t + 256 * k;
        e[k] = hsN[idx] + wv[k] * r1 * w_pa[idx];
        ss2 += e[k] * e[k];
      }
      float r2 = rsqrtf(blockSum(ss2) * (1.f / 2048.f) + EPS);
      float* hs2L = p.hs2 + li * 2048;
#pragma unroll
      for (int k = 0; k < 8; k++) {
        int idx = t + 256 * k;
        xs[idx] = e[k] * r2 * w_pf[idx];
        if (b == 0) hs2L[idx] = e[k];
      }
      __syncthreads();
      // pair 0 (rows gw): prefetched first halves
      {
        const float* g = p.Wg + ((size_t)li * 4096 + gw) * H;
        const float* u = p.Wu + ((size_t)li * 4096 + gw) * H;
        float ag = dot_rest<2048, 1024>(g, xs, lane, dot_pre<4>(preG4, xs, lane));
        float au = dot_rest<2048, 1024>(u, xs, lane, dot_pre<4>(preU4, xs, lane));
        ag = waveSum(ag); au = waveSum(au);
        if (lane == 0) p.actb[li * 4096 + gw] = gelu_t(ag) * au;
      }
      // pair 1 (rows gw+2048)
      {
        int row = gw + 2048;
        const float* g = p.Wg + ((size_t)li * 4096 + row) * H;
        const float* u = p.Wu + ((size_t)li * 4096 + row) * H;
        float ag = 0.f, au = 0.f;
#pragma unroll
        for (int c = lane * 4; c < 2048; c += 256) {
          float4 x4 = *(const float4*)(xs + c);
          ag = dot4(*(const float4*)(g + c), x4, ag);
          au = dot4(*(const float4*)(u + c), x4, au);
        }
        ag = waveSum(ag); au = waveSum(au);
        if (lane == 0) p.actb[li * 4096 + row] = gelu_t(ag) * au;
      }
    }
    float4 preF[8];
    prefetch_row<8>(p.Wd + ((size_t)li * 2048 + gw) * DFF, lane, preF);
    gbar(p.cnt, p.top, p.go, sid); sid++;

    // ============ Stage F: down GEMV (2048 x 4096) ==========================
    {
      const float* x = p.actb + li * 4096;
      const float* wr = p.Wd + ((size_t)li * 2048 + gw) * DFF;
      float s = waveSum(dot_rest<4096, 2048>(wr, x, lane, dot_pre<8>(preF, x, lane)));
      if (lane == 0) p.dnb[li * 2048 + gw] = s;
    }
    float4 preP[8];
    if (gw < 256) prefetch_row<8>(p.Wpg + ((size_t)li * 256 + gw) * H, lane, preP);
    gbar(p.cnt, p.top, p.go, sid); sid++;

    // ============ Stage G: hs3, sl, pl-gate GEMV (256 x 2048) ===============
    if (b < 64) {
      const float* hs2L = p.hs2 + li * 2048;
      const float* dn = p.dnb + li * 2048;
      const float* w_pff = p.lpff + (size_t)li * 2048;
      float dv[8]; float ss = 0.f;
#pragma unroll
      for (int k = 0; k < 8; k++) { dv[k] = dn[t + 256 * k]; ss += dv[k] * dv[k]; }
      float r1 = rsqrtf(blockSum(ss) * (1.f / 2048.f) + EPS);
      float* hs3L = p.hs3 + li * 2048;
#pragma unroll
      for (int k = 0; k < 8; k++) {
        int idx = t + 256 * k;
        float e = hs2L[idx] + dv[k] * r1 * w_pff[idx];
        xs[idx] = e;
        if (b == 0) hs3L[idx] = e;
      }
      float pv = p.projb[li * 256 + t];
      float rp = rsqrtf(blockSum(pv * pv) * (1.f / 256.f) + EPS);
      s_qt[t] = (pv * rp * p.plw[t] + p.plr[li * 256 + t]) * PLE_IN_SCALE;
      __syncthreads();
      float acc = waveSum(dot_pre<8>(preP, xs, lane));
      if (lane == 0) p.gatedb[li * 256 + gw] = gelu_t(acc) * s_qt[gw];
    }
    float4 preH = *(const float4*)(p.Wpp + ((size_t)li * 2048 + gw) * PLD + lane * 4);
    gbar(p.cnt, p.top, p.go, sid); sid++;

    // ============ Stage H: Wpp GEMV (2048 x 256) ============================
    {
      float4 x4 = *(const float4*)(p.gatedb + li * 256 + lane * 4);
      float s = waveSum(dot4(preH, x4, 0.f));
      if (lane == 0) p.plb[li * 2048 + gw] = s;
    }
    // prefetch next layer's QKV row
    hasB = (li + 1 < NL) && (gw < 3072);
    if (hasB) {
      const float* wr;
      if (gw < 2048)      wr = p.Wq + ((size_t)(li + 1) * 2048 + gw) * H;
      else if (gw < 2560) wr = p.Wk + ((size_t)(li + 1) * 512 + (gw - 2048)) * H;
      else                wr = p.Wv + ((size_t)(li + 1) * 512 + (gw - 2560)) * H;
      prefetch_row<8>(wr, lane, preB);
    }
    gbar(p.cnt, p.top, p.go, sid); sid++;
  }

  // ================= final: out = (hs3 + rms(pl)*w_pl) * lsc[7] =============
  if (b == 0) {
    const float* pl = p.plb + 7 * 2048;
    const float* wpl = p.lpl + (size_t)7 * 2048;
    const float* hs3L = p.hs3 + 7 * 2048;
    float pv[8]; float ss = 0.f;
#pragma unroll
    for (int k = 0; k < 8; k++) { pv[k] = pl[t + 256 * k]; ss += pv[k] * pv[k]; }
    float r = rsqrtf(blockSum(ss) * (1.f / 2048.f) + EPS);
    float sc = p.lsc[NL - 1];
#pragma unroll
    for (int k = 0; k < 8; k++) {
      int idx = t + 256 * k;
      p.out[idx] = (hs3L[idx] + pv[k] * r * wpl[idx]) * sc;
    }
  }
}

extern "C" void kernel_launch(void* const* d_in, const int* in_sizes, int n_in,
                              void* d_out, int out_size, void* d_ws, size_t ws_size,
                              hipStream_t stream) {
  MegaP p;
  p.hidden     = (const float*)d_in[0];
  p.mask_full  = (const float*)d_in[1];
  p.um         = (const float*)d_in[3];
  p.plr        = (const float*)d_in[4];
  p.cos_s      = (const float*)d_in[5];
  p.sin_s      = (const float*)d_in[6];
  p.cos_f      = (const float*)d_in[7];
  p.sin_f      = (const float*)d_in[8];
  p.Ksl        = (const float*)d_in[9];
  p.Vsl        = (const float*)d_in[10];
  p.Kfu        = (const float*)d_in[11];
  p.Vfu        = (const float*)d_in[12];
  p.Wq         = (const float*)d_in[13];
  p.Wk         = (const float*)d_in[14];
  p.Wv         = (const float*)d_in[15];
  p.Wo         = (const float*)d_in[16];
  p.qnw        = (const float*)d_in[17];
  p.knw        = (const float*)d_in[18];
  p.lin        = (const float*)d_in[19];
  p.lpa        = (const float*)d_in[20];
  p.lpf        = (const float*)d_in[21];
  p.lpff       = (const float*)d_in[22];
  p.Wg         = (const float*)d_in[23];
  p.Wu         = (const float*)d_in[24];
  p.Wd         = (const float*)d_in[25];
  p.Wpg        = (const float*)d_in[26];
  p.Wpp        = (const float*)d_in[27];
  p.lpl        = (const float*)d_in[28];
  p.lsc        = (const float*)d_in[29];
  p.Wple       = (const float*)d_in[30];
  p.plw        = (const float*)d_in[31];

  float* out = (float*)d_out;
  const size_t KS_SZ = (size_t)7 * 2 * WIN * HD;
  const size_t KF_SZ = (size_t)2 * FULLS * HD;
  p.out   = out;
  p.outKs = out + 2048;
  p.outVs = p.outKs + KS_SZ;
  p.outKf = p.outVs + KS_SZ;
  p.outVf = p.outKf + KF_SZ;

  // ---- workspace: [zeroed int region | float buffers] ----
  int* zi = (int*)d_ws;
  p.cnt  = zi;                          // 56*32 padded x32 = 57344 ints
  p.top  = zi + 57344;                  // 56 padded x32 = 1792
  p.go   = zi + 57344 + 1792;           // 32 padded x32 = 1024
  p.acnt = zi + 57344 + 1792 + 1024;    // 64
  const size_t ZINTS = 57344 + 1792 + 1024 + 64;   // 60224

  float* f = (float*)d_ws + ZINTS;
  p.projb  = f;  f += 2048;
  p.qkvb   = f;  f += NL * 3072;
  p.attnb  = f;  f += NL * 2048;
  p.wob    = f;  f += NL * 2048;
  p.actb   = f;  f += NL * 4096;
  p.dnb    = f;  f += NL * 2048;
  p.gatedb = f;  f += NL * 256;
  p.plb    = f;  f += NL * 2048;
  p.hs_new = f;  f += NL * 2048;
  p.hs2    = f;  f += NL * 2048;
  p.hs3    = f;  f += NL * 2048;
  p.part_o = f;  f += (size_t)NL * NH * MS * 256;
  p.part_ml= f;  f += NL * NH * MS * 2;

  (void)hipMemsetAsync(d_ws, 0, ZINTS * sizeof(int), stream);
  k_mega<<<NB, 256, 0, stream>>>(p);
}

// Round 6
// 677.942 us; speedup vs baseline: 5.7735x; 3.6761x over previous
//
#include <hip/hip_runtime.h>

#define H    2048
#define NH   8
#define NKV  2
#define HD   256
#define DFF  4096
#define PLD  256
#define NL   8
#define WIN  512
#define FULLS 4096
#define EPS  1e-6f
#define ATT_SCALE 0.0625f
#define PLE_PROJ_SCALE 0.022097086912079608f  // 2048^-0.5
#define PLE_IN_SCALE   0.7071067811865476f    // 2^-0.5
#define MS   16
#define NB   512              // persistent grid (2 blocks/CU co-resident, proven r3/r5)
#define NWAVE 2048            // NB*4
#define NGRP 32
#define GSZ  16               // NB/NGRP
#define NSID 56               // barriers: 7 per layer * 8 layers

__device__ __forceinline__ float waveSum(float v) {
#pragma unroll
  for (int o = 32; o; o >>= 1) v += __shfl_xor(v, o);
  return v;
}
__device__ __forceinline__ float waveMax(float v) {
#pragma unroll
  for (int o = 32; o; o >>= 1) v = fmaxf(v, __shfl_xor(v, o));
  return v;
}
__device__ __forceinline__ float blockSum(float v) {
  __shared__ float red[4];
  int lane = threadIdx.x & 63, wid = threadIdx.x >> 6;
  v = waveSum(v);
  if (lane == 0) red[wid] = v;
  __syncthreads();
  float s = red[0] + red[1] + red[2] + red[3];
  __syncthreads();
  return s;
}
__device__ __forceinline__ float gelu_t(float x) {
  float x3 = x * x * x;
  return 0.5f * x * (1.f + tanhf(0.79788456080286536f * (x + 0.044715f * x3)));
}

// agent-scope relaxed store: bypasses L1/L2, lands at LLC (coherence point).
// All inter-stage scalar outputs go through this -> no dirty L2 lines ->
// no wbl2/inv needed anywhere in the barrier protocol.
__device__ __forceinline__ void ast(float* p, float v) {
  __hip_atomic_store(p, v, __ATOMIC_RELAXED, __HIP_MEMORY_SCOPE_AGENT);
}

// ---- device-wide barrier v3: ZERO cache-maintenance ops.
// Entry: every wave drains vmcnt (agent stores ack'd at LLC) then block-syncs.
// Arrival tree + go flags are all RELAXED atomics (LLC-serviced).
// Readers after the barrier use plain loads: every inter-stage buffer address
// is written exactly once per execution (per-layer versioned), so no cache
// holds a stale copy; an L2 miss fetches the current LLC copy.
__device__ __forceinline__ void gbar(int* cnt, int* top, int* go, int sid) {
  asm volatile("s_waitcnt vmcnt(0)" ::: "memory");
  __syncthreads();
  if (threadIdx.x == 0) {
    const int grp = blockIdx.x >> 4;   // /GSZ
    int old = __hip_atomic_fetch_add(cnt + (sid * NGRP + grp) * 32, 1,
                                     __ATOMIC_RELAXED, __HIP_MEMORY_SCOPE_AGENT);
    if (old == GSZ - 1) {
      int o2 = __hip_atomic_fetch_add(top + sid * 32, 1,
                                      __ATOMIC_RELAXED, __HIP_MEMORY_SCOPE_AGENT);
      if (o2 == NGRP - 1) {
        for (int g = 0; g < NGRP; g++)
          __hip_atomic_store(go + g * 32, sid + 1, __ATOMIC_RELAXED,
                             __HIP_MEMORY_SCOPE_AGENT);
      }
    }
    while (__hip_atomic_load(go + grp * 32, __ATOMIC_RELAXED,
                             __HIP_MEMORY_SCOPE_AGENT) <= sid)
      __builtin_amdgcn_s_sleep(2);
  }
  __syncthreads();
}

__device__ __forceinline__ float dot4(float4 w, float4 x, float acc) {
  return fmaf(w.x, x.x, fmaf(w.y, x.y, fmaf(w.z, x.z, fmaf(w.w, x.w, acc))));
}

template <int C>
__device__ __forceinline__ float dotrow(const float* __restrict__ w,
                                        const float* __restrict__ x, int lane) {
  float acc = 0.f;
#pragma unroll
  for (int c = lane * 4; c < C; c += 256)
    acc = dot4(*(const float4*)(w + c), *(const float4*)(x + c), acc);
  return waveSum(acc);
}
template <int NPF>
__device__ __forceinline__ void prefetch_row(const float* __restrict__ w, int lane,
                                             float4* pre) {
#pragma unroll
  for (int k = 0; k < NPF; k++) pre[k] = *(const float4*)(w + lane * 4 + k * 256);
}
template <int NPF>
__device__ __forceinline__ float dot_pre(const float4* pre, const float* __restrict__ x,
                                         int lane) {
  float acc = 0.f;
#pragma unroll
  for (int k = 0; k < NPF; k++)
    acc = dot4(pre[k], *(const float4*)(x + lane * 4 + k * 256), acc);
  return acc;
}
template <int C, int OFS>
__device__ __forceinline__ float dot_rest(const float* __restrict__ w,
                                          const float* __restrict__ x, int lane,
                                          float acc) {
#pragma unroll
  for (int c = OFS + lane * 4; c < C; c += 256)
    acc = dot4(*(const float4*)(w + c), *(const float4*)(x + c), acc);
  return acc;
}

struct MegaP {
  const float *hidden, *mask_full, *um, *plr, *cos_s, *sin_s, *cos_f, *sin_f;
  const float *Ksl, *Vsl, *Kfu, *Vfu;
  const float *Wq, *Wk, *Wv, *Wo, *qnw, *knw, *lin, *lpa, *lpf, *lpff;
  const float *Wg, *Wu, *Wd, *Wpg, *Wpp, *lpl, *lsc, *Wple, *plw;
  float *out, *outKs, *outVs, *outKf, *outVf;
  float *projb, *qkvb, *attnb, *wob, *actb, *dnb, *gatedb, *plb;
  float *hs_new, *hs2, *hs3, *part_o, *part_ml;
  int *cnt, *top, *go, *acnt;
};

__global__ __launch_bounds__(256, 2) void k_mega(MegaP p) {
  const int t = threadIdx.x, lane = t & 63, wid = t >> 6, b = blockIdx.x;
  const int gw = b * 4 + wid;          // 0..2047
  int sid = 0;

  __shared__ __align__(16) float xs[2048];
  __shared__ __align__(16) float s_kr[2][256], s_v[2][256], s_q[256], s_qt[256];
  __shared__ float s_sc[64], s_ml[2];
  __shared__ int s_last;

  float4 preB[8];
  bool hasB = false;

  for (int li = 0; li < NL; li++) {
    const bool isf = (li % 5 == 4);
    const float* cosp = isf ? p.cos_f : p.cos_s;
    const float* sinp = isf ? p.sin_f : p.sin_s;
    float* qkvL = p.qkvb + li * 3072;

    // ============ Stage B: hs_new, xs = rms(hs_new)*w_in, QKV (+PLE at li=0) ====
    {
      float e[8];
      if (li == 0) {
#pragma unroll
        for (int k = 0; k < 8; k++) e[k] = p.hidden[t + 256 * k];
      } else {
        const float* pl  = p.plb + (li - 1) * 2048;
        const float* wpl = p.lpl + (size_t)(li - 1) * 2048;
        const float* hp  = p.hs3 + (li - 1) * 2048;
        float plv[8]; float ss = 0.f;
#pragma unroll
        for (int k = 0; k < 8; k++) { plv[k] = pl[t + 256 * k]; ss += plv[k] * plv[k]; }
        float r1 = rsqrtf(blockSum(ss) * (1.f / 2048.f) + EPS);
        float sc = p.lsc[li - 1];
#pragma unroll
        for (int k = 0; k < 8; k++) {
          int idx = t + 256 * k;
          e[k] = (hp[idx] + plv[k] * r1 * wpl[idx]) * sc;
        }
      }
      float ss2 = 0.f;
#pragma unroll
      for (int k = 0; k < 8; k++) ss2 += e[k] * e[k];
      float r2 = rsqrtf(blockSum(ss2) * (1.f / 2048.f) + EPS);
      const float* w_in = p.lin + (size_t)li * 2048;
      float* hsN = p.hs_new + li * 2048;
#pragma unroll
      for (int k = 0; k < 8; k++) {
        int idx = t + 256 * k;
        xs[idx] = e[k] * r2 * w_in[idx];
        if (b == 0) ast(hsN + idx, e[k]);
      }
      __syncthreads();
      const int nrows = (li == 0) ? 5120 : 3072;
      for (int row = gw; row < nrows; row += NWAVE) {
        const float* wr; const float* xsrc = xs; float* dst; float sc2 = 1.f;
        if (row < 2048)      { wr = p.Wq + ((size_t)li * 2048 + row) * H; dst = qkvL + row; }
        else if (row < 2560) { wr = p.Wk + ((size_t)li * 512 + (row - 2048)) * H; dst = qkvL + row; }
        else if (row < 3072) { wr = p.Wv + ((size_t)li * 512 + (row - 2560)) * H; dst = qkvL + row; }
        else { wr = p.Wple + (size_t)(row - 3072) * H; xsrc = p.hidden;
               dst = p.projb + (row - 3072); sc2 = PLE_PROJ_SCALE; }
        float s;
        if (row == gw && hasB) s = waveSum(dot_pre<8>(preB, xsrc, lane));
        else                   s = dotrow<2048>(wr, xsrc, lane);
        if (lane == 0) ast(dst, s * sc2);
      }
    }
    gbar(p.cnt, p.top, p.go, sid); sid++;

    // ============ Stage C: attention tasks + cache-update tasks =============
    {
      const int S = isf ? FULLS : WIN;
      const int nsp = isf ? 16 : 8;          // attended splits (full: j<1024 only)
      const int natt = NH * nsp;
      const int ncache = isf ? 256 : 32;     // tasks of 4096 float4 each
      const int ntask = natt + ncache;
      const int si = (li < 4) ? li : li - 1;
      const float* Kin = isf ? p.Kfu : p.Ksl + (size_t)si * 2 * WIN * HD;
      const float* Vin = isf ? p.Vfu : p.Vsl + (size_t)si * 2 * WIN * HD;
      float* Ko = isf ? p.outKf : p.outKs + (size_t)si * 2 * WIN * HD;
      float* Vo = isf ? p.outVf : p.outVs + (size_t)si * 2 * WIN * HD;
      float* pO  = p.part_o  + (size_t)li * (NH * MS * 256);
      float* pML = p.part_ml + li * (NH * MS * 2);

      if (b < ntask) {
        // prologue: k rms+rope, v vnorm for both kv heads
        for (int c = 0; c < 2; c++) {
          float kvv = qkvL[2048 + c * 256 + t];
          float rk = rsqrtf(blockSum(kvv * kvv) * (1.f / 256.f) + EPS);
          float kn = kvv * rk * p.knw[li * 256 + t];
          s_qt[t] = kn;
          float vv = qkvL[2560 + c * 256 + t];
          float rv = rsqrtf(blockSum(vv * vv) * (1.f / 256.f) + EPS);  // syncs s_qt
          float rot = (t < 128) ? -s_qt[t + 128] : s_qt[t - 128];
          s_kr[c][t] = kn * cosp[t] + rot * sinp[t];
          s_v[c][t] = vv * rv;
          __syncthreads();
        }
        const int task = b;
        if (task < natt) {
          const int h = task / nsp, split = task % nsp, kvh = h >> 2;
          const int j0 = split * 64;
          float qv = qkvL[h * 256 + t];
          float rq = rsqrtf(blockSum(qv * qv) * (1.f / 256.f) + EPS);
          float qn = qv * rq * p.qnw[li * 256 + t];
          s_qt[t] = qn;
          __syncthreads();
          float rot = (t < 128) ? -s_qt[t + 128] : s_qt[t - 128];
          s_q[t] = qn * cosp[t] + rot * sinp[t];
          __syncthreads();
          // scores
          float4 q4 = ((const float4*)s_q)[lane];
          for (int jl = wid; jl < 64; jl += 4) {
            int j = j0 + jl;
            float4 k4;
            if (!isf) {
              k4 = (j < S - 1) ? ((const float4*)Kin)[((size_t)kvh * S + j + 1) * 64 + lane]
                               : ((const float4*)s_kr[kvh])[lane];
            } else {
              k4 = ((const float4*)Kin)[((size_t)kvh * S + j) * 64 + lane];
              float u = p.um[j];
              if (u != 0.f) {
                float om = 1.f - u;
                float4 nk = ((const float4*)s_kr[kvh])[lane];
                k4.x = k4.x * om + nk.x * u; k4.y = k4.y * om + nk.y * u;
                k4.z = k4.z * om + nk.z * u; k4.w = k4.w * om + nk.w * u;
              }
            }
            float pp = q4.x * k4.x + q4.y * k4.y + q4.z * k4.z + q4.w * k4.w;
            pp = waveSum(pp);
            if (lane == 0) s_sc[jl] = pp * ATT_SCALE + (isf ? p.mask_full[j] : 0.f);
          }
          __syncthreads();
          if (wid == 0) {
            float v = s_sc[lane];
            float m = waveMax(v);
            float e = expf(v - m);
            s_sc[lane] = e;
            float l = waveSum(e);
            if (lane == 0) { s_ml[0] = m; s_ml[1] = l; }
          }
          __syncthreads();
          // PV
          float o = 0.f;
#pragma unroll 8
          for (int jl = 0; jl < 64; jl++) {
            int j = j0 + jl;
            float vj;
            if (!isf) {
              vj = (j < S - 1) ? Vin[((size_t)kvh * S + j + 1) * 256 + t] : s_v[kvh][t];
            } else {
              vj = Vin[((size_t)kvh * S + j) * 256 + t];
              float u = p.um[j];
              if (u != 0.f) vj = vj * (1.f - u) + s_v[kvh][t] * u;
            }
            o = fmaf(s_sc[jl], vj, o);
          }
          ast(pO + ((size_t)h * MS + split) * 256 + t, o);
          if (t < 2) ast(pML + (h * MS + split) * 2 + t, s_ml[t]);
          // drain this block's agent stores, then relaxed-elect the combiner
          asm volatile("s_waitcnt vmcnt(0)" ::: "memory");
          __syncthreads();
          if (t == 0) {
            int old = __hip_atomic_fetch_add(p.acnt + li * NH + h, 1,
                                             __ATOMIC_RELAXED, __HIP_MEMORY_SCOPE_AGENT);
            s_last = (old == nsp - 1);
          }
          __syncthreads();
          if (s_last) {
            float M = -INFINITY;
            for (int s2 = 0; s2 < nsp; s2++) M = fmaxf(M, pML[(h * MS + s2) * 2]);
            float L = 0.f, oo = 0.f;
            for (int s2 = 0; s2 < nsp; s2++) {
              float m = pML[(h * MS + s2) * 2];
              float l = pML[(h * MS + s2) * 2 + 1];
              float f = expf(m - M);
              L += l * f;
              oo = fmaf(pO[((size_t)h * MS + s2) * 256 + t], f, oo);
            }
            ast(p.attnb + li * 2048 + h * 256 + t, oo / L);
          }
        } else {
          // cache task: 4096 float4 slice of [K|V][kv][pos][64]
          int ci = task - natt;
          const int fK = 2 * S * 64;
          const float4* Ki4 = (const float4*)Kin;
          const float4* Vi4 = (const float4*)Vin;
          float4* Ko4 = (float4*)Ko;
          float4* Vo4 = (float4*)Vo;
#pragma unroll
          for (int k = 0; k < 16; k++) {
            int idx = ci * 4096 + k * 256 + t;
            int isV = idx >= fK;
            int rid = isV ? idx - fK : idx;
            int kvh = rid / (S * 64);
            int rem = rid % (S * 64);
            int j = rem >> 6, d4 = rem & 63;
            const float4* in4 = isV ? Vi4 : Ki4;
            const float4* nn4 = (const float4*)(isV ? s_v[kvh] : s_kr[kvh]);
            float4 v;
            if (!isf) {
              v = (j < S - 1) ? in4[((size_t)kvh * S + j + 1) * 64 + d4] : nn4[d4];
            } else {
              v = in4[rid];
              float u = p.um[j];
              if (u != 0.f) {
                float om = 1.f - u;
                float4 nv = nn4[d4];
                v.x = v.x * om + nv.x * u; v.y = v.y * om + nv.y * u;
                v.z = v.z * om + nv.z * u; v.w = v.w * om + nv.w * u;
              }
            }
            (isV ? Vo4 : Ko4)[rid] = v;
          }
        }
      }
    }
    // prefetch Wo row for stage D (flies during the barrier)
    float4 preD[8];
    prefetch_row<8>(p.Wo + ((size_t)li * 2048 + gw) * H, lane, preD);
    gbar(p.cnt, p.top, p.go, sid); sid++;

    // ============ Stage D: Wo GEMV (2048 x 2048) ============================
    {
      float s = waveSum(dot_pre<8>(preD, p.attnb + li * 2048, lane));
      if (lane == 0) ast(p.wob + li * 2048 + gw, s);
    }
    float4 preG4[4], preU4[4];
    prefetch_row<4>(p.Wg + ((size_t)li * 4096 + gw) * H, lane, preG4);
    prefetch_row<4>(p.Wu + ((size_t)li * 4096 + gw) * H, lane, preU4);
    gbar(p.cnt, p.top, p.go, sid); sid++;

    // ============ Stage E: hs2, xs = rms(hs2)*w_pf, gate/up GEMV ============
    {
      const float* hsN = p.hs_new + li * 2048;
      const float* wo = p.wob + li * 2048;
      const float* w_pa = p.lpa + (size_t)li * 2048;
      const float* w_pf = p.lpf + (size_t)li * 2048;
      float wv[8]; float ss = 0.f;
#pragma unroll
      for (int k = 0; k < 8; k++) { wv[k] = wo[t + 256 * k]; ss += wv[k] * wv[k]; }
      float r1 = rsqrtf(blockSum(ss) * (1.f / 2048.f) + EPS);
      float e[8]; float ss2 = 0.f;
#pragma unroll
      for (int k = 0; k < 8; k++) {
        int idx = t + 256 * k;
        e[k] = hsN[idx] + wv[k] * r1 * w_pa[idx];
        ss2 += e[k] * e[k];
      }
      float r2 = rsqrtf(blockSum(ss2) * (1.f / 2048.f) + EPS);
      float* hs2L = p.hs2 + li * 2048;
#pragma unroll
      for (int k = 0; k < 8; k++) {
        int idx = t + 256 * k;
        xs[idx] = e[k] * r2 * w_pf[idx];
        if (b == 0) ast(hs2L + idx, e[k]);
      }
      __syncthreads();
      // pair 0 (rows gw): prefetched first halves
      {
        const float* g = p.Wg + ((size_t)li * 4096 + gw) * H;
        const float* u = p.Wu + ((size_t)li * 4096 + gw) * H;
        float ag = dot_rest<2048, 1024>(g, xs, lane, dot_pre<4>(preG4, xs, lane));
        float au = dot_rest<2048, 1024>(u, xs, lane, dot_pre<4>(preU4, xs, lane));
        ag = waveSum(ag); au = waveSum(au);
        if (lane == 0) ast(p.actb + li * 4096 + gw, gelu_t(ag) * au);
      }
      // pair 1 (rows gw+2048)
      {
        int row = gw + 2048;
        const float* g = p.Wg + ((size_t)li * 4096 + row) * H;
        const float* u = p.Wu + ((size_t)li * 4096 + row) * H;
        float ag = 0.f, au = 0.f;
#pragma unroll
        for (int c = lane * 4; c < 2048; c += 256) {
          float4 x4 = *(const float4*)(xs + c);
          ag = dot4(*(const float4*)(g + c), x4, ag);
          au = dot4(*(const float4*)(u + c), x4, au);
        }
        ag = waveSum(ag); au = waveSum(au);
        if (lane == 0) ast(p.actb + li * 4096 + row, gelu_t(ag) * au);
      }
    }
    float4 preF[8];
    prefetch_row<8>(p.Wd + ((size_t)li * 2048 + gw) * DFF, lane, preF);
    gbar(p.cnt, p.top, p.go, sid); sid++;

    // ============ Stage F: down GEMV (2048 x 4096) ==========================
    {
      const float* x = p.actb + li * 4096;
      const float* wr = p.Wd + ((size_t)li * 2048 + gw) * DFF;
      float s = waveSum(dot_rest<4096, 2048>(wr, x, lane, dot_pre<8>(preF, x, lane)));
      if (lane == 0) ast(p.dnb + li * 2048 + gw, s);
    }
    float4 preP[8];
    if (gw < 256) prefetch_row<8>(p.Wpg + ((size_t)li * 256 + gw) * H, lane, preP);
    gbar(p.cnt, p.top, p.go, sid); sid++;

    // ============ Stage G: hs3, sl, pl-gate GEMV (256 x 2048) ===============
    if (b < 64) {
      const float* hs2L = p.hs2 + li * 2048;
      const float* dn = p.dnb + li * 2048;
      const float* w_pff = p.lpff + (size_t)li * 2048;
      float dv[8]; float ss = 0.f;
#pragma unroll
      for (int k = 0; k < 8; k++) { dv[k] = dn[t + 256 * k]; ss += dv[k] * dv[k]; }
      float r1 = rsqrtf(blockSum(ss) * (1.f / 2048.f) + EPS);
      float* hs3L = p.hs3 + li * 2048;
#pragma unroll
      for (int k = 0; k < 8; k++) {
        int idx = t + 256 * k;
        float e = hs2L[idx] + dv[k] * r1 * w_pff[idx];
        xs[idx] = e;
        if (b == 0) ast(hs3L + idx, e);
      }
      float pv = p.projb[li * 256 + t];
      float rp = rsqrtf(blockSum(pv * pv) * (1.f / 256.f) + EPS);
      s_qt[t] = (pv * rp * p.plw[t] + p.plr[li * 256 + t]) * PLE_IN_SCALE;
      __syncthreads();
      float acc = waveSum(dot_pre<8>(preP, xs, lane));
      if (lane == 0) ast(p.gatedb + li * 256 + gw, gelu_t(acc) * s_qt[gw]);
    }
    float4 preH = *(const float4*)(p.Wpp + ((size_t)li * 2048 + gw) * PLD + lane * 4);
    gbar(p.cnt, p.top, p.go, sid); sid++;

    // ============ Stage H: Wpp GEMV (2048 x 256) ============================
    {
      float4 x4 = *(const float4*)(p.gatedb + li * 256 + lane * 4);
      float s = waveSum(dot4(preH, x4, 0.f));
      if (lane == 0) ast(p.plb + li * 2048 + gw, s);
    }
    // prefetch next layer's QKV row
    hasB = (li + 1 < NL) && (gw < 3072);
    if (hasB) {
      const float* wr;
      if (gw < 2048)      wr = p.Wq + ((size_t)(li + 1) * 2048 + gw) * H;
      else if (gw < 2560) wr = p.Wk + ((size_t)(li + 1) * 512 + (gw - 2048)) * H;
      else                wr = p.Wv + ((size_t)(li + 1) * 512 + (gw - 2560)) * H;
      prefetch_row<8>(wr, lane, preB);
    }
    gbar(p.cnt, p.top, p.go, sid); sid++;
  }

  // ================= final: out = (hs3 + rms(pl)*w_pl) * lsc[7] =============
  if (b == 0) {
    const float* pl = p.plb + 7 * 2048;
    const float* wpl = p.lpl + (size_t)7 * 2048;
    const float* hs3L = p.hs3 + 7 * 2048;
    float pv[8]; float ss = 0.f;
#pragma unroll
    for (int k = 0; k < 8; k++) { pv[k] = pl[t + 256 * k]; ss += pv[k] * pv[k]; }
    float r = rsqrtf(blockSum(ss) * (1.f / 2048.f) + EPS);
    float sc = p.lsc[NL - 1];
#pragma unroll
    for (int k = 0; k < 8; k++) {
      int idx = t + 256 * k;
      p.out[idx] = (hs3L[idx] + pv[k] * r * wpl[idx]) * sc;
    }
  }
}

extern "C" void kernel_launch(void* const* d_in, const int* in_sizes, int n_in,
                              void* d_out, int out_size, void* d_ws, size_t ws_size,
                              hipStream_t stream) {
  MegaP p;
  p.hidden     = (const float*)d_in[0];
  p.mask_full  = (const float*)d_in[1];
  p.um         = (const float*)d_in[3];
  p.plr        = (const float*)d_in[4];
  p.cos_s      = (const float*)d_in[5];
  p.sin_s      = (const float*)d_in[6];
  p.cos_f      = (const float*)d_in[7];
  p.sin_f      = (const float*)d_in[8];
  p.Ksl        = (const float*)d_in[9];
  p.Vsl        = (const float*)d_in[10];
  p.Kfu        = (const float*)d_in[11];
  p.Vfu        = (const float*)d_in[12];
  p.Wq         = (const float*)d_in[13];
  p.Wk         = (const float*)d_in[14];
  p.Wv         = (const float*)d_in[15];
  p.Wo         = (const float*)d_in[16];
  p.qnw        = (const float*)d_in[17];
  p.knw        = (const float*)d_in[18];
  p.lin        = (const float*)d_in[19];
  p.lpa        = (const float*)d_in[20];
  p.lpf        = (const float*)d_in[21];
  p.lpff       = (const float*)d_in[22];
  p.Wg         = (const float*)d_in[23];
  p.Wu         = (const float*)d_in[24];
  p.Wd         = (const float*)d_in[25];
  p.Wpg        = (const float*)d_in[26];
  p.Wpp        = (const float*)d_in[27];
  p.lpl        = (const float*)d_in[28];
  p.lsc        = (const float*)d_in[29];
  p.Wple       = (const float*)d_in[30];
  p.plw        = (const float*)d_in[31];

  float* out = (float*)d_out;
  const size_t KS_SZ = (size_t)7 * 2 * WIN * HD;
  const size_t KF_SZ = (size_t)2 * FULLS * HD;
  p.out   = out;
  p.outKs = out + 2048;
  p.outVs = p.outKs + KS_SZ;
  p.outKf = p.outVs + KS_SZ;
  p.outVf = p.outKf + KF_SZ;

  // ---- workspace: [zeroed int region | float buffers] ----
  int* zi = (int*)d_ws;
  p.cnt  = zi;                          // 56*32 padded x32 = 57344 ints
  p.top  = zi + 57344;                  // 56 padded x32 = 1792
  p.go   = zi + 57344 + 1792;           // 32 padded x32 = 1024
  p.acnt = zi + 57344 + 1792 + 1024;    // 64
  const size_t ZINTS = 57344 + 1792 + 1024 + 64;   // 60224

  float* f = (float*)d_ws + ZINTS;
  p.projb  = f;  f += 2048;
  p.qkvb   = f;  f += NL * 3072;
  p.attnb  = f;  f += NL * 2048;
  p.wob    = f;  f += NL * 2048;
  p.actb   = f;  f += NL * 4096;
  p.dnb    = f;  f += NL * 2048;
  p.gatedb = f;  f += NL * 256;
  p.plb    = f;  f += NL * 2048;
  p.hs_new = f;  f += NL * 2048;
  p.hs2    = f;  f += NL * 2048;
  p.hs3    = f;  f += NL * 2048;
  p.part_o = f;  f += (size_t)NL * NH * MS * 256;
  p.part_ml= f;  f += NL * NH * MS * 2;

  (void)hipMemsetAsync(d_ws, 0, ZINTS * sizeof(int), stream);
  k_mega<<<NB, 256, 0, stream>>>(p);
}